// Round 14
// baseline (144.307 us; speedup 1.0000x reference)
//
#include <hip/hip_runtime.h>
#include <hip/hip_bf16.h>
#include <math.h>

#define DDIM 7168
#define NEXP 256
#define NGRP 8
#define TOPKG 4
#define TOPK 8
#define ROUTE_SCALE 2.5f

#define BM 128
#define BN 256
#define BK 32
#define KSPLIT 4
#define KPER (DDIM / KSPLIT)        // 1792
#define NSTEP (KPER / BK)           // 56
#define NKTILE (DDIM / BK)          // 224
#define BT_ELEMS (NEXP * BK * 2)    // 16384 shorts = 32 KB B-tile
#define AT_FLOATS (BM * BK)         // 4096 f32 = 16 KB A-tile

typedef __attribute__((ext_vector_type(8))) short bf16x8;
typedef __attribute__((ext_vector_type(4))) float f32x4;
typedef unsigned int u32;
typedef unsigned short ushort_t;

static __device__ __forceinline__ ushort_t bf16_rne(float f) {
    u32 b = __float_as_uint(f);
    u32 r = (b + 0x7fffu + ((b >> 16) & 1u)) >> 16;
    return (ushort_t)r;
}
static __device__ __forceinline__ float bf16_to_f32(ushort_t h) {
    return __uint_as_float(((u32)h) << 16);
}
// hi = bf16(f) via HW cvt; lo = bf16(f - hi)
static __device__ __forceinline__ void split_elem(float f, short& h, short& l) {
    union { __hip_bfloat16 b; short s; } cv;
    cv.b = __float2bfloat16(f);
    h = cv.s;
    float hf = __uint_as_float(((u32)(ushort_t)cv.s) << 16);
    cv.b = __float2bfloat16(f - hf);
    l = cv.s;
}

// ---------------------------------------------------------------------------
// Kernel 0: split w into hi/lo bf16, fragment-linear per BK=32 k-tile.
// Tile (32 KB): [pass(2)][fn(16)][lane(64)][8 bf16]  (R3/R13-proven)
// ---------------------------------------------------------------------------
__global__ __launch_bounds__(256) void wsplit_kernel(const float* __restrict__ w,
                                                     short* __restrict__ wsp)
{
    const int kt = blockIdx.x;      // 0..223
    const int e  = threadIdx.x;     // expert 0..255
    const float* wp = w + (size_t)e * DDIM + (size_t)kt * BK;
    short* tb = wsp + (size_t)kt * BT_ELEMS;
    const int fn = e >> 4, er = e & 15;
    #pragma unroll
    for (int jg = 0; jg < 4; jg++) {
        float f[8];
        *(float4*)&f[0] = *(const float4*)(wp + jg * 8);
        *(float4*)&f[4] = *(const float4*)(wp + jg * 8 + 4);
        ushort_t h[8], l[8];
        #pragma unroll
        for (int j = 0; j < 8; j++) {
            h[j] = bf16_rne(f[j]);
            l[j] = bf16_rne(f[j] - bf16_to_f32(h[j]));
        }
        const int lane = jg * 16 + er;
        *(uint4*)(tb + ((size_t)(0 * 16 + fn) * 64 + lane) * 8) = *(uint4*)h;
        *(uint4*)(tb + ((size_t)(1 * 16 + fn) * 64 + lane) * 8) = *(uint4*)l;
    }
}

// ---------------------------------------------------------------------------
// Kernel 1: split-precision bf16 MFMA GEMM — coalesced-A (R13-proven) +
// counted-vmcnt 3-buffer pipeline + square 64x64 wave tiles.
//  * BM=128 x BN=256, 8 waves (2wm x 4wn): LDS reads 16KB/wave/step for
//    48 MFMA -> per-step MFMA (1863 cyc/CU) > LDS (1000 cyc) = MFMA-bound.
//  * 3-buffer staging, 2-step landing lead. Per-thread issue group per step
//    = 4 B-glds + 2 A-glds = 6. Top-of-step wait: vmcnt(6) retires exactly
//    group(st) (issued at st-2); barrier makes it block-wide; NEVER vmcnt(0)
//    in the main loop (T4). WAR: buf[(st+2)%3] last read at st-1, reads
//    retired before barrier(st) (lgkmcnt(0) per wave).
//  * A source pre-swizzled/coalesced (8 lines/instr), linear LDS dest,
//    XOR-swizzled read — conflict-free round trip (R13-verified).
// grid = 64 mt x 4 ksp = 256 (1 block/CU); no setprio (m190).
// ---------------------------------------------------------------------------
__global__ __launch_bounds__(512, 2) void gemm_split_kernel(
    const float* __restrict__ x, const short* __restrict__ wsp,
    float* __restrict__ part, int Btok)
{
    __shared__ short Blds[3][BT_ELEMS];    // 3 x 32 KB
    __shared__ float Alds[3][AT_FLOATS];   // 3 x 16 KB   (total 144 KB)

    const int bid  = blockIdx.x;
    const int xcd  = bid & 7;
    const int ksp  = xcd & 3;
    const int mt   = (bid >> 3) * 2 + (xcd >> 2);   // 0..63, bijective
    const int m0   = mt * BM;
    const int kbase = ksp * KPER;
    const int t    = threadIdx.x;
    const int wid  = t >> 6, lane = t & 63;
    const int wm   = wid >> 2, wn = wid & 3;
    const int lr   = lane & 15, lg = lane >> 4;

    const short* wt0 = wsp + (size_t)(ksp * NSTEP) * BT_ELEMS;

    // A staging: wave w stages rows w*16..w*16+15; instr i covers rows
    // w*16+i*8+(l>>3) at swizzled k-slot (l&7)^((l>>3)&7) -> full 128B lines.
    const int arow0 = wid * 16 + (lane >> 3);                 // + i*8
    const int akoff = 4 * ((lane & 7) ^ ((lane >> 3) & 7));
    const float* asrc0 = x + (size_t)(m0 + arow0) * DDIM + kbase + akoff;
    const size_t arow_step = (size_t)8 * DDIM;
    const int adst0 = wid * 2048 + lane * 16;                 // + i*1024 bytes

#define STAGE_B(stp, bptr) do {                                                            \
        const short* gt_ = wt0 + (size_t)(stp) * BT_ELEMS;                                 \
        _Pragma("unroll")                                                                  \
        for (int i_ = 0; i_ < 4; i_++) {                                                   \
            const int off_ = wid * 4096 + i_ * 1024;                                       \
            __builtin_amdgcn_global_load_lds(                                              \
                (const __attribute__((address_space(1))) u32*)((const char*)gt_ + off_ + lane * 16), \
                (__attribute__((address_space(3))) u32*)((char*)(bptr) + off_),            \
                16, 0, 0);                                                                 \
        } } while (0)

#define STAGE_A(stp, aptr) do {                                                            \
        _Pragma("unroll")                                                                  \
        for (int i_ = 0; i_ < 2; i_++) {                                                   \
            __builtin_amdgcn_global_load_lds(                                              \
                (const __attribute__((address_space(1))) u32*)(asrc0 + (size_t)i_ * arow_step + (size_t)(stp) * BK), \
                (__attribute__((address_space(3))) u32*)((char*)(aptr) + adst0 + i_ * 1024), \
                16, 0, 0);                                                                 \
        } } while (0)

    f32x4 acc[4][4];
    #pragma unroll
    for (int i = 0; i < 4; i++)
        #pragma unroll
        for (int j = 0; j < 4; j++) acc[i][j] = (f32x4){0.f, 0.f, 0.f, 0.f};

    // rotating buffer pointers: _r = holds step st, _1 = st+1, _2 = dest for st+2
    short* pB_r = &Blds[0][0]; short* pB_1 = &Blds[1][0]; short* pB_2 = &Blds[2][0];
    float* pA_r = &Alds[0][0]; float* pA_1 = &Alds[1][0]; float* pA_2 = &Alds[2][0];

    // ---- prologue: groups for steps 0 and 1 (B then A per group) ----
    STAGE_B(0, pB_r); STAGE_A(0, pA_r);
    STAGE_B(1, pB_1); STAGE_A(1, pA_1);

    for (int st = 0; st < NSTEP; st++) {
        // retire exactly group(st): 12 outstanding -> 6 (tail: drain all)
        if (st < NSTEP - 1) { asm volatile("s_waitcnt vmcnt(6)" ::: "memory"); }
        else                { asm volatile("s_waitcnt vmcnt(0)" ::: "memory"); }
        asm volatile("s_waitcnt lgkmcnt(0)" ::: "memory");
        __builtin_amdgcn_s_barrier();
        asm volatile("" ::: "memory");

        // ---- issue group(st+2) into the buffer read at step st-1 ----
        if (st + 2 < NSTEP) { STAGE_B(st + 2, pB_2); STAGE_A(st + 2, pA_2); }

        // ---- A fragments from LDS (swizzled read, conflict-free) + convert ----
        const char* ab = (const char*)pA_r;
        bf16x8 ah[4], al[4];
        #pragma unroll
        for (int fm = 0; fm < 4; fm++) {
            const int row = wm * 64 + fm * 16 + lr;
            const int rb  = row * 128;
            const int sw  = (lr & 7) << 4;
            float fr[8];
            *(float4*)&fr[0] = *(const float4*)(ab + rb + ((lg * 32) ^ sw));
            *(float4*)&fr[4] = *(const float4*)(ab + rb + ((lg * 32 + 16) ^ sw));
            union { bf16x8 v; short s[8]; } H, L;
            #pragma unroll
            for (int j = 0; j < 8; j++)
                split_elem(fr[j], H.s[j], L.s[j]);
            ah[fm] = H.v;
            al[fm] = L.v;
        }

        // ---- B fragments (lane-linear) + MFMA, pass-major ----
        bf16x8 bhv[4], blv[4];
        #pragma unroll
        for (int fn = 0; fn < 4; fn++) {
            bhv[fn] = *(const bf16x8*)&pB_r[((size_t)(0 * 16 + wn * 4 + fn) * 64 + lane) * 8];
            blv[fn] = *(const bf16x8*)&pB_r[((size_t)(1 * 16 + wn * 4 + fn) * 64 + lane) * 8];
        }
        #pragma unroll
        for (int fn = 0; fn < 4; fn++)
            #pragma unroll
            for (int fm = 0; fm < 4; fm++)
                acc[fm][fn] = __builtin_amdgcn_mfma_f32_16x16x32_bf16(ah[fm], bhv[fn], acc[fm][fn], 0, 0, 0);
        #pragma unroll
        for (int fn = 0; fn < 4; fn++)
            #pragma unroll
            for (int fm = 0; fm < 4; fm++)
                acc[fm][fn] = __builtin_amdgcn_mfma_f32_16x16x32_bf16(ah[fm], blv[fn], acc[fm][fn], 0, 0, 0);
        #pragma unroll
        for (int fn = 0; fn < 4; fn++)
            #pragma unroll
            for (int fm = 0; fm < 4; fm++)
                acc[fm][fn] = __builtin_amdgcn_mfma_f32_16x16x32_bf16(al[fm], bhv[fn], acc[fm][fn], 0, 0, 0);

        // ---- rotate buffers ----
        { short* tb_ = pB_r; pB_r = pB_1; pB_1 = pB_2; pB_2 = tb_; }
        { float* ta_ = pA_r; pA_r = pA_1; pA_1 = pA_2; pA_2 = ta_; }
    }
#undef STAGE_B
#undef STAGE_A

    // ---- epilogue: fp32 partials (C/D map: col=lane&15, row=(lane>>4)*4+reg) ----
    float* pp = part + (size_t)ksp * (size_t)Btok * NEXP;
    #pragma unroll
    for (int fm = 0; fm < 4; fm++) {
        const int row0 = m0 + wm * 64 + fm * 16 + lg * 4;
        #pragma unroll
        for (int fn = 0; fn < 4; fn++) {
            const int col = wn * 64 + fn * 16 + lr;
            #pragma unroll
            for (int rr = 0; rr < 4; rr++)
                pp[(size_t)(row0 + rr) * NEXP + col] = acc[fm][fn][rr];
        }
    }
}

// ---------------------------------------------------------------------------
// Kernel 2: reduce split-K partials + sigmoid + full gating, one wave per row.
// (unchanged — proven)
// ---------------------------------------------------------------------------
__global__ __launch_bounds__(256) void gate_kernel(
    const float* __restrict__ part, const float* __restrict__ bias,
    float* __restrict__ out_w, float* __restrict__ out_i, int B)
{
    const int lane = threadIdx.x & 63;
    const int wid  = threadIdx.x >> 6;
    const int row  = blockIdx.x * 4 + wid;
    if (row >= B) return;

    const size_t plane = (size_t)B * NEXP;
    const float* pr = part + (size_t)row * NEXP + lane * 4;
    float4 v0 = *(const float4*)(pr);
    float4 v1 = *(const float4*)(pr + plane);
    float4 v2 = *(const float4*)(pr + 2 * plane);
    float4 v3 = *(const float4*)(pr + 3 * plane);
    float sc[4] = { v0.x + v1.x + v2.x + v3.x,
                    v0.y + v1.y + v2.y + v3.y,
                    v0.z + v1.z + v2.z + v3.z,
                    v0.w + v1.w + v2.w + v3.w };
    float4 bv = *(const float4*)(bias + lane * 4);
    const float bb[4] = { bv.x, bv.y, bv.z, bv.w };

    float so[4], sb[4];
    #pragma unroll
    for (int j = 0; j < 4; j++) {
        so[j] = 1.0f / (1.0f + expf(-sc[j]));
        sb[j] = so[j] + bb[j];
    }

    float m1 = sb[0], m2 = -INFINITY;
    #pragma unroll
    for (int j = 1; j < 4; j++) {
        if (sb[j] > m1)      { m2 = m1; m1 = sb[j]; }
        else if (sb[j] > m2) { m2 = sb[j]; }
    }
    #pragma unroll
    for (int m = 1; m <= 4; m <<= 1) {
        float o1 = __shfl_xor(m1, m);
        float o2 = __shfl_xor(m2, m);
        float hi = fmaxf(m1, o1);
        float lo = fminf(m1, o1);
        m1 = hi;
        m2 = fmaxf(lo, fmaxf(m2, o2));
    }
    float gscore = m1 + m2;
    int g = lane >> 3;

    float gs[NGRP];
    #pragma unroll
    for (int gg = 0; gg < NGRP; gg++) gs[gg] = __shfl(gscore, gg * 8);
    int rank = 0;
    #pragma unroll
    for (int gg = 0; gg < NGRP; gg++) {
        if (gg == g) continue;
        if (gs[gg] > gs[g] || (gs[gg] == gs[g] && gg < g)) rank++;
    }
    const bool selg = (rank < TOPKG);
    float mv[4];
    #pragma unroll
    for (int j = 0; j < 4; j++) mv[j] = selg ? sb[j] : -INFINITY;

    float wsel[TOPK];
    int   isel[TOPK];
    float wsum = 0.f;
    #pragma unroll
    for (int it = 0; it < TOPK; it++) {
        float v = mv[0]; int jj = 0;
        #pragma unroll
        for (int j = 1; j < 4; j++)
            if (mv[j] > v) { v = mv[j]; jj = j; }
        int gi = (lane << 2) | jj;
        #pragma unroll
        for (int m = 1; m < 64; m <<= 1) {
            float ov = __shfl_xor(v, m);
            int   oi = __shfl_xor(gi, m);
            if (ov > v || (ov == v && oi < gi)) { v = ov; gi = oi; }
        }
        int slot = gi & 3, src = gi >> 2;
        float cand = (slot == 0) ? so[0] : (slot == 1) ? so[1] : (slot == 2) ? so[2] : so[3];
        float sval = __shfl(cand, src);
        wsel[it] = sval; isel[it] = gi; wsum += sval;
        if (lane == src) mv[slot] = -INFINITY;
    }

    if (lane == 0) {
        float scl = ROUTE_SCALE / wsum;
        #pragma unroll
        for (int it = 0; it < TOPK; it++) {
            out_w[(size_t)row * TOPK + it] = wsel[it] * scl;
            out_i[(size_t)row * TOPK + it] = (float)isel[it];
        }
    }
}

extern "C" void kernel_launch(void* const* d_in, const int* in_sizes, int n_in,
                              void* d_out, int out_size, void* d_ws, size_t ws_size,
                              hipStream_t stream)
{
    const float* x    = (const float*)d_in[0];
    const float* w    = (const float*)d_in[1];
    const float* bias = (const float*)d_in[2];
    const int B = in_sizes[0] / DDIM;           // 8192

    // ws layout: [ part: 4 * B * 256 f32 = 32 MB ][ wsp: 224 tiles * 32 KB = 7.34 MB ]
    float* part = (float*)d_ws;
    short* wsp  = (short*)((char*)d_ws + (size_t)KSPLIT * B * NEXP * sizeof(float));

    float* out_w = (float*)d_out;
    float* out_i = out_w + (size_t)B * TOPK;

    hipLaunchKernelGGL(wsplit_kernel, dim3(NKTILE), dim3(256), 0, stream, w, wsp);
    hipLaunchKernelGGL(gemm_split_kernel, dim3((B / BM) * KSPLIT), dim3(512), 0, stream,
                       x, wsp, part, B);
    hipLaunchKernelGGL(gate_kernel, dim3((B + 3) / 4), dim3(256), 0, stream,
                       part, bias, out_w, out_i, B);
}

// Round 15
// 141.386 us; speedup vs baseline: 1.0207x; 1.0207x over previous
//
#include <hip/hip_runtime.h>
#include <hip/hip_bf16.h>
#include <math.h>

#define DDIM 7168
#define NEXP 256
#define NGRP 8
#define TOPKG 4
#define TOPK 8
#define ROUTE_SCALE 2.5f

#define BM 128
#define BN 128
#define BK 32
#define KSPLIT 4
#define KPER (DDIM / KSPLIT)        // 1792
#define NSTEP (KPER / BK)           // 56
#define NKTILE (DDIM / BK)          // 224
#define BT_ELEMS (BN * BK * 2)      // 8192 shorts = 16 KB B-tile (per nh half)
#define AT_FLOATS (BM * BK)         // 4096 f32 = 16 KB A-tile

typedef __attribute__((ext_vector_type(8))) short bf16x8;
typedef __attribute__((ext_vector_type(4))) float f32x4;
typedef unsigned int u32;
typedef unsigned short ushort_t;

static __device__ __forceinline__ ushort_t bf16_rne(float f) {
    u32 b = __float_as_uint(f);
    u32 r = (b + 0x7fffu + ((b >> 16) & 1u)) >> 16;
    return (ushort_t)r;
}
static __device__ __forceinline__ float bf16_to_f32(ushort_t h) {
    return __uint_as_float(((u32)h) << 16);
}
// hi = bf16(f) via HW cvt; lo = bf16(f - hi)
static __device__ __forceinline__ void split_elem(float f, short& h, short& l) {
    union { __hip_bfloat16 b; short s; } cv;
    cv.b = __float2bfloat16(f);
    h = cv.s;
    float hf = __uint_as_float(((u32)(ushort_t)cv.s) << 16);
    cv.b = __float2bfloat16(f - hf);
    l = cv.s;
}

// ---------------------------------------------------------------------------
// Kernel 0: split w into hi/lo bf16, fragment-linear tiles per (kt, nh).
// Tile (16 KB): [split(2)][fn(8)][lane(64)][8 bf16]  — R6-proven layout.
// element = split of W[nh*128 + fn*16 + (lane&15)][kt*32 + (lane>>4)*8 + j]
// ---------------------------------------------------------------------------
__global__ __launch_bounds__(256) void wsplit_kernel(const float* __restrict__ w,
                                                     short* __restrict__ wsp)
{
    const int kt = blockIdx.x;      // 0..223
    const int e  = threadIdx.x;     // expert 0..255
    const float* wp = w + (size_t)e * DDIM + (size_t)kt * BK;
    const int nh = e >> 7, fn = (e >> 4) & 7, er = e & 15;
    short* tb = wsp + ((size_t)kt * 2 + nh) * BT_ELEMS;
    #pragma unroll
    for (int jg = 0; jg < 4; jg++) {
        float f[8];
        *(float4*)&f[0] = *(const float4*)(wp + jg * 8);
        *(float4*)&f[4] = *(const float4*)(wp + jg * 8 + 4);
        ushort_t h[8], l[8];
        #pragma unroll
        for (int j = 0; j < 8; j++) {
            h[j] = bf16_rne(f[j]);
            l[j] = bf16_rne(f[j] - bf16_to_f32(h[j]));
        }
        const int lane = jg * 16 + er;
        *(uint4*)(tb + ((size_t)(0 * 8 + fn) * 64 + lane) * 8) = *(uint4*)h;
        *(uint4*)(tb + ((size_t)(1 * 8 + fn) * 64 + lane) * 8) = *(uint4*)l;
    }
}

// ---------------------------------------------------------------------------
// Kernel 1: split-precision bf16 MFMA GEMM — 64x64 wave tiles + 2 blocks/CU.
// R13/R14 decomposition: R13 (32x64 tiles, 2 blk/CU) was LDS-BW-bound
// (0.5 KB LDS-read per MFMA -> 53 us > 43.5 us MFMA floor); R14 (64x64,
// 1 blk/CU) lost block overlap. This round gets BOTH: 4-wave blocks of
// 64x64 (0.33 KB/MFMA -> LDS 35 us < MFMA floor) with LDS 64 KB -> 2
// blocks/CU. Skeleton = R13's proven one-__syncthreads 2-buffer 1-ahead.
//  * A source pre-swizzled/coalesced (8 full 128B lines per instr), linear
//    LDS dest, XOR-swizzled read: phys granule p = s ^ (row&7). Verified:
//    write lane l instr i -> row wid*32+i*8+(l>>3), p=(l&7), logical slot
//    (l&7)^(row&7); read at p=s^(row&7) retrieves slot s. Round-trip OK.
// grid = 64 mt x 2 nh x 4 ksp = 512 (2 blocks/CU); 256 thr = 4 waves
// (2 wm x 2 wn), 48 MFMA/wave/step. XCD: bid&7 -> (ksp,nh), 896 KB w-slice
// L2-resident per XCD.
// ---------------------------------------------------------------------------
__global__ __launch_bounds__(256, 2) void gemm_split_kernel(
    const float* __restrict__ x, const short* __restrict__ wsp,
    float* __restrict__ part, int Btok)
{
    __shared__ short Blds[2][BT_ELEMS];    // 2 x 16 KB
    __shared__ float Alds[2][AT_FLOATS];   // 2 x 16 KB   (total 64 KB)

    const int bid  = blockIdx.x;
    const int xcd  = bid & 7;
    const int ksp  = xcd & 3;
    const int nh   = xcd >> 2;
    const int mt   = bid >> 3;             // 0..63
    const int m0   = mt * BM;
    const int kbase = ksp * KPER;
    const int t    = threadIdx.x;
    const int wid  = t >> 6, lane = t & 63;
    const int wm   = wid >> 1, wn = wid & 1;
    const int lr   = lane & 15, lg = lane >> 4;

    // B tile for step st: wsp[((ksp*NSTEP + st)*2 + nh) * BT_ELEMS]
    const short* wt0 = wsp + ((size_t)(ksp * NSTEP) * 2 + nh) * BT_ELEMS;

    // A staging: wave w stages rows w*32..w*32+31 (4 instrs of 8 rows each);
    // instr i: lane l -> row w*32+i*8+(l>>3), swizzled k-slot (l&7)^((l>>3)&7)
    const int arow0 = wid * 32 + (lane >> 3);
    const int akoff = 4 * ((lane & 7) ^ ((lane >> 3) & 7));
    const float* asrc0 = x + (size_t)(m0 + arow0) * DDIM + kbase + akoff;
    const size_t arow_step = (size_t)8 * DDIM;
    const int adst0 = wid * 4096 + lane * 16;   // + i*1024 bytes

#define STAGE_B(stp, buf) do {                                                             \
        const short* gt_ = wt0 + (size_t)(stp) * 2 * BT_ELEMS;                             \
        _Pragma("unroll")                                                                  \
        for (int i_ = 0; i_ < 4; i_++) {                                                   \
            const int off_ = wid * 4096 + i_ * 1024;                                       \
            __builtin_amdgcn_global_load_lds(                                              \
                (const __attribute__((address_space(1))) u32*)((const char*)gt_ + off_ + lane * 16), \
                (__attribute__((address_space(3))) u32*)((char*)&Blds[buf][0] + off_),     \
                16, 0, 0);                                                                 \
        } } while (0)

#define STAGE_A(stp, buf) do {                                                             \
        _Pragma("unroll")                                                                  \
        for (int i_ = 0; i_ < 4; i_++) {                                                   \
            __builtin_amdgcn_global_load_lds(                                              \
                (const __attribute__((address_space(1))) u32*)(asrc0 + (size_t)i_ * arow_step + (size_t)(stp) * BK), \
                (__attribute__((address_space(3))) u32*)((char*)&Alds[buf][0] + adst0 + i_ * 1024), \
                16, 0, 0);                                                                 \
        } } while (0)

    f32x4 acc[4][4];
    #pragma unroll
    for (int i = 0; i < 4; i++)
        #pragma unroll
        for (int j = 0; j < 4; j++) acc[i][j] = (f32x4){0.f, 0.f, 0.f, 0.f};

    // ---- prologue ----
    STAGE_B(0, 0);
    STAGE_A(0, 0);

    for (int st = 0; st < NSTEP; st++) {
        const int cur = st & 1;
        // waits vmcnt(0)+lgkmcnt(0): A(st)/B(st) DMA resident; prior reads done
        __syncthreads();

        // ---- issue next-step staging (lands during this step's compute) ----
        if (st + 1 < NSTEP) {
            STAGE_B(st + 1, cur ^ 1);
            STAGE_A(st + 1, cur ^ 1);
        }

        // ---- A fragments from LDS (swizzled read) + hi/lo convert ----
        const char* ab = (const char*)&Alds[cur][0];
        bf16x8 ah[4], al[4];
        #pragma unroll
        for (int fm = 0; fm < 4; fm++) {
            const int row = wm * 64 + fm * 16 + lr;
            const int rb  = row * 128;
            const int sw  = (lr & 7) << 4;          // row&7 == lr&7 (offsets %16==0)
            float fr[8];
            *(float4*)&fr[0] = *(const float4*)(ab + rb + ((lg * 32) ^ sw));
            *(float4*)&fr[4] = *(const float4*)(ab + rb + ((lg * 32 + 16) ^ sw));
            union { bf16x8 v; short s[8]; } H, L;
            #pragma unroll
            for (int j = 0; j < 8; j++)
                split_elem(fr[j], H.s[j], L.s[j]);
            ah[fm] = H.v;
            al[fm] = L.v;
        }

        // ---- B fragments (lane-linear) + MFMA, pass-major ----
        bf16x8 bhv[4], blv[4];
        #pragma unroll
        for (int fn = 0; fn < 4; fn++) {
            bhv[fn] = *(const bf16x8*)&Blds[cur][((size_t)(0 * 8 + wn * 4 + fn) * 64 + lane) * 8];
            blv[fn] = *(const bf16x8*)&Blds[cur][((size_t)(1 * 8 + wn * 4 + fn) * 64 + lane) * 8];
        }
        #pragma unroll
        for (int fn = 0; fn < 4; fn++)
            #pragma unroll
            for (int fm = 0; fm < 4; fm++)
                acc[fm][fn] = __builtin_amdgcn_mfma_f32_16x16x32_bf16(ah[fm], bhv[fn], acc[fm][fn], 0, 0, 0);
        #pragma unroll
        for (int fn = 0; fn < 4; fn++)
            #pragma unroll
            for (int fm = 0; fm < 4; fm++)
                acc[fm][fn] = __builtin_amdgcn_mfma_f32_16x16x32_bf16(ah[fm], blv[fn], acc[fm][fn], 0, 0, 0);
        #pragma unroll
        for (int fn = 0; fn < 4; fn++)
            #pragma unroll
            for (int fm = 0; fm < 4; fm++)
                acc[fm][fn] = __builtin_amdgcn_mfma_f32_16x16x32_bf16(al[fm], bhv[fn], acc[fm][fn], 0, 0, 0);
    }
#undef STAGE_B
#undef STAGE_A

    // ---- epilogue: fp32 partials (C/D map: col=lane&15, row=(lane>>4)*4+reg) ----
    float* pp = part + (size_t)ksp * (size_t)Btok * NEXP;
    #pragma unroll
    for (int fm = 0; fm < 4; fm++) {
        const int row0 = m0 + wm * 64 + fm * 16 + lg * 4;
        #pragma unroll
        for (int fn = 0; fn < 4; fn++) {
            const int col = nh * 128 + wn * 64 + fn * 16 + lr;
            #pragma unroll
            for (int rr = 0; rr < 4; rr++)
                pp[(size_t)(row0 + rr) * NEXP + col] = acc[fm][fn][rr];
        }
    }
}

// ---------------------------------------------------------------------------
// Kernel 2: reduce split-K partials + sigmoid + full gating, one wave per row.
// (unchanged — proven)
// ---------------------------------------------------------------------------
__global__ __launch_bounds__(256) void gate_kernel(
    const float* __restrict__ part, const float* __restrict__ bias,
    float* __restrict__ out_w, float* __restrict__ out_i, int B)
{
    const int lane = threadIdx.x & 63;
    const int wid  = threadIdx.x >> 6;
    const int row  = blockIdx.x * 4 + wid;
    if (row >= B) return;

    const size_t plane = (size_t)B * NEXP;
    const float* pr = part + (size_t)row * NEXP + lane * 4;
    float4 v0 = *(const float4*)(pr);
    float4 v1 = *(const float4*)(pr + plane);
    float4 v2 = *(const float4*)(pr + 2 * plane);
    float4 v3 = *(const float4*)(pr + 3 * plane);
    float sc[4] = { v0.x + v1.x + v2.x + v3.x,
                    v0.y + v1.y + v2.y + v3.y,
                    v0.z + v1.z + v2.z + v3.z,
                    v0.w + v1.w + v2.w + v3.w };
    float4 bv = *(const float4*)(bias + lane * 4);
    const float bb[4] = { bv.x, bv.y, bv.z, bv.w };

    float so[4], sb[4];
    #pragma unroll
    for (int j = 0; j < 4; j++) {
        so[j] = 1.0f / (1.0f + expf(-sc[j]));
        sb[j] = so[j] + bb[j];
    }

    float m1 = sb[0], m2 = -INFINITY;
    #pragma unroll
    for (int j = 1; j < 4; j++) {
        if (sb[j] > m1)      { m2 = m1; m1 = sb[j]; }
        else if (sb[j] > m2) { m2 = sb[j]; }
    }
    #pragma unroll
    for (int m = 1; m <= 4; m <<= 1) {
        float o1 = __shfl_xor(m1, m);
        float o2 = __shfl_xor(m2, m);
        float hi = fmaxf(m1, o1);
        float lo = fminf(m1, o1);
        m1 = hi;
        m2 = fmaxf(lo, fmaxf(m2, o2));
    }
    float gscore = m1 + m2;
    int g = lane >> 3;

    float gs[NGRP];
    #pragma unroll
    for (int gg = 0; gg < NGRP; gg++) gs[gg] = __shfl(gscore, gg * 8);
    int rank = 0;
    #pragma unroll
    for (int gg = 0; gg < NGRP; gg++) {
        if (gg == g) continue;
        if (gs[gg] > gs[g] || (gs[gg] == gs[g] && gg < g)) rank++;
    }
    const bool selg = (rank < TOPKG);
    float mv[4];
    #pragma unroll
    for (int j = 0; j < 4; j++) mv[j] = selg ? sb[j] : -INFINITY;

    float wsel[TOPK];
    int   isel[TOPK];
    float wsum = 0.f;
    #pragma unroll
    for (int it = 0; it < TOPK; it++) {
        float v = mv[0]; int jj = 0;
        #pragma unroll
        for (int j = 1; j < 4; j++)
            if (mv[j] > v) { v = mv[j]; jj = j; }
        int gi = (lane << 2) | jj;
        #pragma unroll
        for (int m = 1; m < 64; m <<= 1) {
            float ov = __shfl_xor(v, m);
            int   oi = __shfl_xor(gi, m);
            if (ov > v || (ov == v && oi < gi)) { v = ov; gi = oi; }
        }
        int slot = gi & 3, src = gi >> 2;
        float cand = (slot == 0) ? so[0] : (slot == 1) ? so[1] : (slot == 2) ? so[2] : so[3];
        float sval = __shfl(cand, src);
        wsel[it] = sval; isel[it] = gi; wsum += sval;
        if (lane == src) mv[slot] = -INFINITY;
    }

    if (lane == 0) {
        float scl = ROUTE_SCALE / wsum;
        #pragma unroll
        for (int it = 0; it < TOPK; it++) {
            out_w[(size_t)row * TOPK + it] = wsel[it] * scl;
            out_i[(size_t)row * TOPK + it] = (float)isel[it];
        }
    }
}

extern "C" void kernel_launch(void* const* d_in, const int* in_sizes, int n_in,
                              void* d_out, int out_size, void* d_ws, size_t ws_size,
                              hipStream_t stream)
{
    const float* x    = (const float*)d_in[0];
    const float* w    = (const float*)d_in[1];
    const float* bias = (const float*)d_in[2];
    const int B = in_sizes[0] / DDIM;           // 8192

    // ws layout: [ part: 4 * B * 256 f32 = 32 MB ][ wsp: 224*2 tiles * 16 KB = 7.34 MB ]
    float* part = (float*)d_ws;
    short* wsp  = (short*)((char*)d_ws + (size_t)KSPLIT * B * NEXP * sizeof(float));

    float* out_w = (float*)d_out;
    float* out_i = out_w + (size_t)B * TOPK;

    hipLaunchKernelGGL(wsplit_kernel, dim3(NKTILE), dim3(256), 0, stream, w, wsp);
    hipLaunchKernelGGL(gemm_split_kernel, dim3((B / BM) * 2 * KSPLIT), dim3(256), 0, stream,
                       x, wsp, part, B);
    hipLaunchKernelGGL(gate_kernel, dim3((B + 3) / 4), dim3(256), 0, stream,
                       part, bias, out_w, out_i, B);
}